// Round 13
// baseline (527.856 us; speedup 1.0000x reference)
//
#include <hip/hip_runtime.h>
#include <hip/hip_cooperative_groups.h>
#include <math.h>

namespace cg = cooperative_groups;

#define B_ 4096
#define D_ 512
#define G_ 128
#define N_ (G_*G_)        // 16384
#define NTP 64            // number of 256-wide n tiles (partials per row)
#define THR_ 0.95f
#define IMAX_ 0x7FFFFFFF

typedef float f32x4 __attribute__((ext_vector_type(4)));
typedef _Float16 half8 __attribute__((ext_vector_type(8)));

// ---------------- packed (value,index) helpers for argmin ----------------
__device__ __forceinline__ unsigned long long packmin(float v, int n) {
    unsigned u = __float_as_uint(v);
    u ^= (u & 0x80000000u) ? 0xFFFFFFFFu : 0x80000000u;
    return ((unsigned long long)u << 32) | (unsigned)n;
}
__device__ __forceinline__ void unpackmin(unsigned long long pkt, float* v, int* n) {
    unsigned u = (unsigned)(pkt >> 32);
    u = (u & 0x80000000u) ? (u ^ 0x80000000u) : ~u;
    *v = __uint_as_float(u);
    *n = (int)(unsigned)pkt;
}

// ---------------- MFMA score GEMM tile body: 256x256, 8 waves, r7/r11-proven 4-phase ----------------
// r12 lesson: compiler re-sinks ds_reads regardless of source order (VGPR stayed 128);
// source-level repipelining is a no-op at this structure. This is the verified 105us form.

#define PH_WAIT_(N) asm volatile("s_waitcnt vmcnt(" #N ")" ::: "memory")
#define PH_WAIT(N) PH_WAIT_(N)
#define WAITLGKM0 asm volatile("s_waitcnt lgkmcnt(0)" ::: "memory")
#define SBAR __builtin_amdgcn_s_barrier()
#define SCHED0 __builtin_amdgcn_sched_barrier(0)
#define PRIO1 __builtin_amdgcn_s_setprio(1)
#define PRIO0 __builtin_amdgcn_s_setprio(0)

#define STAGE_HALF(GBASE, LOFF, TAU, H) do { \
    __builtin_amdgcn_global_load_lds( \
        (const __attribute__((address_space(1))) void*)((GBASE) + (size_t)(H) * (128 * D_) + (TAU) * 64 + srcoff0), \
        (__attribute__((address_space(3))) void*)(smem + (LOFF) + (((TAU) & 1) << 15) + ((H) << 14) + ldsoff0), 16, 0, 0); \
    __builtin_amdgcn_global_load_lds( \
        (const __attribute__((address_space(1))) void*)((GBASE) + (size_t)(H) * (128 * D_) + (TAU) * 64 + srcoff1), \
        (__attribute__((address_space(3))) void*)(smem + (LOFF) + (((TAU) & 1) << 15) + ((H) << 14) + ldsoff1), 16, 0, 0); \
} while (0)

#define TILE(TAU, S1, S3, S4, DO_W, VM4) do { \
    half8 af[4][2], bl[2][2], bh[2][2]; \
    _Pragma("unroll") for (int mi = 0; mi < 4; mi++) { \
        af[mi][0] = *(const half8*)(smem + (((TAU) & 1) << 15) + sA + mi * 2048 + swz0); \
        af[mi][1] = *(const half8*)(smem + (((TAU) & 1) << 15) + sA + mi * 2048 + swz1); } \
    _Pragma("unroll") for (int ni = 0; ni < 2; ni++) { \
        bl[ni][0] = *(const half8*)(smem + 65536 + (((TAU) & 1) << 15) + sB + ni * 2048 + swz0); \
        bl[ni][1] = *(const half8*)(smem + 65536 + (((TAU) & 1) << 15) + sB + ni * 2048 + swz1); } \
    if (S1) STAGE_HALF(Abase, 0, (TAU) + 1, 1); \
    SBAR; WAITLGKM0; SCHED0; PRIO1; \
    _Pragma("unroll") for (int mi = 0; mi < 4; mi++) \
      _Pragma("unroll") for (int ni = 0; ni < 2; ni++) { \
        acc[mi][ni] = __builtin_amdgcn_mfma_f32_16x16x32_f16(af[mi][0], bl[ni][0], acc[mi][ni], 0, 0, 0); \
        acc[mi][ni] = __builtin_amdgcn_mfma_f32_16x16x32_f16(af[mi][1], bl[ni][1], acc[mi][ni], 0, 0, 0); } \
    PRIO0; SCHED0; SBAR; \
    _Pragma("unroll") for (int ni = 0; ni < 2; ni++) { \
        bh[ni][0] = *(const half8*)(smem + 65536 + (((TAU) & 1) << 15) + sB + (ni + 2) * 2048 + swz0); \
        bh[ni][1] = *(const half8*)(smem + 65536 + (((TAU) & 1) << 15) + sB + (ni + 2) * 2048 + swz1); } \
    SBAR; WAITLGKM0; SCHED0; PRIO1; \
    _Pragma("unroll") for (int mi = 0; mi < 4; mi++) \
      _Pragma("unroll") for (int ni = 0; ni < 2; ni++) { \
        acc[mi][ni + 2] = __builtin_amdgcn_mfma_f32_16x16x32_f16(af[mi][0], bh[ni][0], acc[mi][ni + 2], 0, 0, 0); \
        acc[mi][ni + 2] = __builtin_amdgcn_mfma_f32_16x16x32_f16(af[mi][1], bh[ni][1], acc[mi][ni + 2], 0, 0, 0); } \
    PRIO0; SCHED0; SBAR; \
    _Pragma("unroll") for (int mi = 0; mi < 4; mi++) { \
        af[mi][0] = *(const half8*)(smem + (((TAU) & 1) << 15) + sA + (mi + 4) * 2048 + swz0); \
        af[mi][1] = *(const half8*)(smem + (((TAU) & 1) << 15) + sA + (mi + 4) * 2048 + swz1); } \
    if (S3) STAGE_HALF(Wbase, 65536, (TAU) + 2, 0); \
    SBAR; WAITLGKM0; SCHED0; PRIO1; \
    _Pragma("unroll") for (int mi = 0; mi < 4; mi++) \
      _Pragma("unroll") for (int ni = 0; ni < 2; ni++) { \
        acc[mi + 4][ni + 2] = __builtin_amdgcn_mfma_f32_16x16x32_f16(af[mi][0], bh[ni][0], acc[mi + 4][ni + 2], 0, 0, 0); \
        acc[mi + 4][ni + 2] = __builtin_amdgcn_mfma_f32_16x16x32_f16(af[mi][1], bh[ni][1], acc[mi + 4][ni + 2], 0, 0, 0); } \
    PRIO0; SCHED0; SBAR; \
    if (S4) { STAGE_HALF(Abase, 0, (TAU) + 2, 0); STAGE_HALF(Wbase, 65536, (TAU) + 2, 1); } \
    if (DO_W) PH_WAIT(VM4); \
    SBAR; PRIO1; \
    _Pragma("unroll") for (int mi = 0; mi < 4; mi++) \
      _Pragma("unroll") for (int ni = 0; ni < 2; ni++) { \
        acc[mi + 4][ni] = __builtin_amdgcn_mfma_f32_16x16x32_f16(af[mi][0], bl[ni][0], acc[mi + 4][ni], 0, 0, 0); \
        acc[mi + 4][ni] = __builtin_amdgcn_mfma_f32_16x16x32_f16(af[mi][1], bl[ni][1], acc[mi + 4][ni], 0, 0, 0); } \
    PRIO0; SCHED0; SBAR; \
} while (0)

__device__ __forceinline__ void score_tile_body(
    int o, const _Float16* __restrict__ Ah, const _Float16* __restrict__ Wh,
    const float* __restrict__ wnorm,
    const int* __restrict__ labels, const int* __restrict__ clabels,
    float* __restrict__ pminv, int* __restrict__ pmini,
    float* __restrict__ pcminv, int* __restrict__ pcmini)
{
    __shared__ __align__(16) char smem[131072];  // A: 2x32KB @0, B: 2x32KB @64KB

    const int tid  = threadIdx.x;
    const int lane = tid & 63;
    const int wave = tid >> 6;
    const int wm = wave >> 2, wn = wave & 3;     // 2M x 4N wave grid; 128x64 per wave
    const int c = lane & 15, quad = lane >> 4;

    const int xcd = o & 7, idx = o >> 3;
    const int ntile = (xcd << 3) | (idx & 7);
    const int mtile = idx >> 3;
    const int m0 = mtile * 256, n0 = ntile * 256;

    const _Float16* Abase = Ah + (size_t)m0 * D_;
    const _Float16* Wbase = Wh + (size_t)n0 * D_;

    const int i0 = tid, i1 = 512 + tid;
    const int rl0 = i0 >> 3, sl0 = i0 & 7, rl1 = i1 >> 3, sl1 = i1 & 7;
    const size_t srcoff0 = (size_t)rl0 * D_ + ((sl0 ^ (rl0 & 7)) << 3);
    const size_t srcoff1 = (size_t)rl1 * D_ + ((sl1 ^ (rl1 & 7)) << 3);
    const int ldsoff0 = i0 << 4, ldsoff1 = i1 << 4;

    const int sA = (wm * 128 + c) * 128;
    const int sB = (wn * 64 + c) * 128;
    const int swz0 = ((0 * 4 + quad) ^ (c & 7)) << 4;   // kk=0
    const int swz1 = ((1 * 4 + quad) ^ (c & 7)) << 4;   // kk=1

    f32x4 acc[8][4];
    #pragma unroll
    for (int i = 0; i < 8; i++)
        #pragma unroll
        for (int j = 0; j < 4; j++)
            acc[i][j] = (f32x4){0.f, 0.f, 0.f, 0.f};

    STAGE_HALF(Abase, 0, 0, 0);
    STAGE_HALF(Wbase, 65536, 0, 0);
    STAGE_HALF(Wbase, 65536, 0, 1);
    STAGE_HALF(Abase, 0, 0, 1);
    STAGE_HALF(Abase, 0, 1, 0);
    STAGE_HALF(Wbase, 65536, 1, 0);
    STAGE_HALF(Wbase, 65536, 1, 1);
    PH_WAIT(6); SBAR;

    TILE(0, 1, 1, 1, 1, 6);
    TILE(1, 1, 1, 1, 1, 6);
    TILE(2, 1, 1, 1, 1, 6);
    TILE(3, 1, 1, 1, 1, 6);
    TILE(4, 1, 1, 1, 1, 6);
    TILE(5, 1, 1, 1, 1, 6);
    TILE(6, 1, 0, 0, 1, 0);
    TILE(7, 0, 0, 0, 0, 0);

    __syncthreads();   // GEMM done; reuse smem as [256][64] u64 candidate table

    const unsigned long long ID = (0xFF800000ull << 32) | 0x7FFFFFFFull;  // (+inf, IMAX)
    float wnl[4]; int cll[4];
    #pragma unroll
    for (int ni = 0; ni < 4; ni++) {
        int n = n0 + wn * 64 + ni * 16 + c;
        wnl[ni] = wnorm[n];
        cll[ni] = clabels[n];
    }

    unsigned long long (*tbl)[64] = (unsigned long long (*)[64])smem;  // 128KB exactly
    unsigned long long cbst[8][4];

    #pragma unroll
    for (int mi = 0; mi < 8; mi++) {
        #pragma unroll
        for (int r = 0; r < 4; r++) {
            int rowl = wm * 128 + mi * 16 + quad * 4 + r;   // 0..255 in block
            int lb = labels[m0 + rowl];
            unsigned long long bb = ID, cb = ID;
            #pragma unroll
            for (int ni = 0; ni < 4; ni++) {
                float s = fmaf(-2.f, acc[mi][ni][r], wnl[ni]);
                unsigned long long pk = packmin(s, n0 + wn * 64 + ni * 16 + c);
                bb = bb < pk ? bb : pk;
                if (cll[ni] == lb) cb = cb < pk ? cb : pk;
            }
            tbl[rowl][(wn * 16 + c) ^ (rowl & 15)] = bb;   // XOR slot: caps conflicts 4-way
            cbst[mi][r] = cb;
        }
    }
    __syncthreads();
    if (tid < 256) {
        int row = tid;
        unsigned long long m = ID;
        #pragma unroll
        for (int j = 0; j < 64; j++) {
            unsigned long long v = tbl[row][j ^ (row & 15)];
            m = m < v ? m : v;
        }
        float v; int n; unpackmin(m, &v, &n);
        size_t pp = (size_t)(m0 + row) * NTP + ntile;
        pminv[pp] = v; pmini[pp] = n;
    }
    __syncthreads();
    #pragma unroll
    for (int mi = 0; mi < 8; mi++)
        #pragma unroll
        for (int r = 0; r < 4; r++) {
            int rowl = wm * 128 + mi * 16 + quad * 4 + r;
            tbl[rowl][(wn * 16 + c) ^ (rowl & 15)] = cbst[mi][r];
        }
    __syncthreads();
    if (tid < 256) {
        int row = tid;
        unsigned long long m = ID;
        #pragma unroll
        for (int j = 0; j < 64; j++) {
            unsigned long long v = tbl[row][j ^ (row & 15)];
            m = m < v ? m : v;
        }
        float v; int n; unpackmin(m, &v, &n);
        size_t pp = (size_t)(m0 + row) * NTP + ntile;
        pcminv[pp] = v; pcmini[pp] = n;
    }
    __syncthreads();   // safe re-stage of smem by a subsequent call
}

// ================= cooperative mega-kernel: prep | score | reduce+scatter | final =================
// 256 blocks x 512 threads, 128KB LDS -> exactly 1 block/CU x 256 CUs (co-resident).
// 3 grid syncs replace 3 dispatch boundaries. All phase loops have exact uniform trip counts.
__global__ __launch_bounds__(512, 2) void mega_kernel(
    const float* __restrict__ A, const int* __restrict__ labels,
    const float* __restrict__ W, const int* __restrict__ clabels,
    const float* __restrict__ crel,
    const int* __restrict__ epoch_p, const int* __restrict__ maxep_p,
    _Float16* __restrict__ Ahi, _Float16* __restrict__ Whi,
    float* __restrict__ wnorm,
    float* __restrict__ pminv, int* __restrict__ pmini,
    float* __restrict__ pcminv, int* __restrict__ pcmini,
    int* __restrict__ bmu, float* __restrict__ sum_min,
    float* __restrict__ out0, float* __restrict__ out1,
    float* __restrict__ S, float* __restrict__ count, int fusedS)
{
    cg::grid_group grid = cg::this_grid();
    const int tid  = threadIdx.x;
    const int blk  = blockIdx.x;              // 0..255
    const int gtid = blk * 512 + tid;         // 0..131071
    const int GS   = 256 * 512;

    // ---- phase 1: prep (A split, W split + wnorm, zero count/sum_min (+S)) ----
    {
        const float4 z = {0.f, 0.f, 0.f, 0.f};
        #pragma unroll
        for (int it = 0; it < 4; it++) {          // 524288 float4 of A
            int i = gtid + it * GS;
            float4 v = ((const float4*)A)[i];
            float vv[4] = {v.x, v.y, v.z, v.w};
            union { _Float16 h[4]; uint64_t u64; } H;
            #pragma unroll
            for (int j = 0; j < 4; j++) H.h[j] = (_Float16)vv[j];
            ((uint64_t*)Ahi)[i] = H.u64;
        }
        const int t = tid & 63;
        #pragma unroll
        for (int it = 0; it < 8; it++) {          // 16384 W rows, 2048 wave-groups
            int n = (gtid >> 6) + it * (GS >> 6);
            const float* row = W + (size_t)n * D_;
            float4 a = ((const float4*)row)[t];
            float4 bq = ((const float4*)row)[t + 64];
            float av[4] = {a.x, a.y, a.z, a.w}, bv[4] = {bq.x, bq.y, bq.z, bq.w};
            union { _Float16 h[4]; uint64_t u64; } Ha, Hb;
            #pragma unroll
            for (int j = 0; j < 4; j++) { Ha.h[j] = (_Float16)av[j]; Hb.h[j] = (_Float16)bv[j]; }
            ((uint64_t*)(Whi + (size_t)n * D_))[t]       = Ha.u64;
            ((uint64_t*)(Whi + (size_t)n * D_ + 256))[t] = Hb.u64;
            float s = a.x*a.x + a.y*a.y + a.z*a.z + a.w*a.w
                    + bq.x*bq.x + bq.y*bq.y + bq.z*bq.z + bq.w*bq.w;
            #pragma unroll
            for (int off = 32; off > 0; off >>= 1) s += __shfl_down(s, off, 64);
            if (t == 0) wnorm[n] = s;
        }
        if (gtid < N_ / 4) ((float4*)count)[gtid] = z;
        if (gtid < 65) sum_min[gtid] = 0.f;
        if (fusedS) {
            #pragma unroll
            for (int it = 0; it < 16; it++)
                ((float4*)S)[(size_t)gtid + (size_t)it * GS] = z;
        }
    }
    __threadfence();
    grid.sync();

    // ---- phase 2: score GEMM + per-tile argmin (grid-stride over 1024 tiles) ----
    for (int o = blk; o < 1024; o += 256)
        score_tile_body(o, Ahi, Whi, wnorm, labels, clabels,
                        pminv, pmini, pcminv, pcmini);
    __threadfence();
    grid.sync();

    // ---- phase 3 (aliased-S fallback only): zero S after score ----
    if (!fusedS) {
        const float4 z = {0.f, 0.f, 0.f, 0.f};
        #pragma unroll
        for (int it = 0; it < 16; it++)
            ((float4*)S)[(size_t)gtid + (size_t)it * GS] = z;
        __threadfence();
        grid.sync();
    }

    // ---- phase 4: reduce (one wave per row) + wave-coalesced scatter ----
    {
        const int l = tid & 63;
        #pragma unroll
        for (int it = 0; it < 2; it++) {          // 4096 rows, 2048 wave-slots
            int rw = (gtid >> 6) + it * (GS >> 6);
            size_t p = (size_t)rw * NTP + l;
            unsigned long long bb = packmin(pminv[p], pmini[p]);
            unsigned long long cb = packmin(pcminv[p], pcmini[p]);

            const float* arow = A + (size_t)rw * D_;
            float4 xa = ((const float4*)arow)[l];
            float4 xb = ((const float4*)arow)[l + 64];
            float xs = xa.x*xa.x + xa.y*xa.y + xa.z*xa.z + xa.w*xa.w
                     + xb.x*xb.x + xb.y*xb.y + xb.z*xb.z + xb.w*xb.w;

            #pragma unroll
            for (int off = 1; off < 64; off <<= 1) {
                unsigned long long ob = __shfl_xor(bb, off, 64);
                bb = bb < ob ? bb : ob;
                unsigned long long oc = __shfl_xor(cb, off, 64);
                cb = cb < oc ? cb : oc;
                xs += __shfl_xor(xs, off, 64);
            }

            float bv; int bn; unpackmin(bb, &bv, &bn);
            float cv; int cn; unpackmin(cb, &cv, &cn);

            if (l == 0) {
                bmu[rw] = bn;
                float md = xs + bv;
                if (md < 0.f) md = 0.f;
                atomicAdd(&sum_min[rw & 63], md);
                atomicAdd(&count[bn], 1.0f);
            }

            float rel = crel[cn] / 100.0f;
            float sc = (rel >= THR_) ? 0.01f * rel : 0.f;
            const float* wrow = W + (size_t)cn * D_;
            float4 wa = ((const float4*)wrow)[l];
            float4 wb = ((const float4*)wrow)[l + 64];
            float4 oa, ob4;
            oa.x = sc * (wa.x - xa.x); oa.y = sc * (wa.y - xa.y);
            oa.z = sc * (wa.z - xa.z); oa.w = sc * (wa.w - xa.w);
            ob4.x = sc * (wb.x - xb.x); ob4.y = sc * (wb.y - xb.y);
            ob4.z = sc * (wb.z - xb.z); ob4.w = sc * (wb.w - xb.w);
            float* orow = out0 + (size_t)rw * D_;
            ((float4*)orow)[l]      = oa;
            ((float4*)orow)[l + 64] = ob4;

            float* Sr = S + (size_t)bn * D_;
            #pragma unroll
            for (int k = 0; k < 8; k++)           // wave-coalesced atomic rounds
                atomicAdd(&Sr[k * 64 + l], arow[k * 64 + l]);
        }
    }
    __threadfence();
    grid.sync();

    // ---- phase 5: final (XCD-chunked grid-stride; stencil L2-resident) ----
    {
        __shared__ float gsum_s;
        if (tid == 0) {
            float s = 0.f;
            for (int i = 0; i < 64; i++) s += sum_min[i];
            gsum_s = s;
        }
        __syncthreads();
        const bool gate = gsum_s > 1e-4f * (float)B_;

        int ep = epoch_p[0], me = maxep_p[0];
        float progress = (me > 0) ? (float)(me - ep) / (float)me : 0.f;
        progress = fminf(fmaxf(progress, 0.f), 1.f);
        float p2 = progress * progress;
        int ctx = (int)(p2 * p2 * 2.0f);
        float lr = 0.05f + progress * 0.15f;

        const int x = blk & 7, wsub = blk >> 3;   // XCD, block-within-XCD
        for (int it = 0; it < 16; it++) {         // 2M float4 total; XCD quarter contiguous
            size_t i4 = (size_t)x * 262144 + (size_t)it * 16384 + (size_t)wsub * 512 + tid;
            int n = (int)(i4 >> 7);
            int d4 = (int)(i4 & 127);
            float4 s4 = ((const float4*)W)[i4];   // som == W
            float4 ov = s4;
            if (gate) {
                int i = n / G_, j = n % G_;
                float4 nu = {0.f, 0.f, 0.f, 0.f};
                float dn = 0.f;
                for (int di = -ctx; di <= ctx; di++) {
                    int ia = i - di; if (ia < 0 || ia >= G_) continue;
                    for (int dj = -ctx; dj <= ctx; dj++) {
                        int jb = j - dj; if (jb < 0 || jb >= G_) continue;
                        int ad = abs(di), aj = abs(dj);
                        int cheb = ad > aj ? ad : aj;
                        float coef = ldexpf(lr, -cheb);
                        float4 t4 = ((const float4*)S)[(size_t)(jb * G_ + ia) * 128 + d4];
                        nu.x += coef * t4.x; nu.y += coef * t4.y;
                        nu.z += coef * t4.z; nu.w += coef * t4.w;
                        dn += coef * count[jb * G_ + ia];
                    }
                }
                ov.x = s4.x + nu.x - s4.x * dn;
                ov.y = s4.y + nu.y - s4.y * dn;
                ov.z = s4.z + nu.z - s4.z * dn;
                ov.w = s4.w + nu.w - s4.w * dn;
            }
            ((float4*)out1)[i4] = ov;
        }
    }
}

// ================= fallback path (r11-proven 4-dispatch pipeline) =================
__global__ __launch_bounds__(256) void prep_kernel(
    const float* __restrict__ A, const float* __restrict__ W,
    _Float16* __restrict__ Ahi, _Float16* __restrict__ Whi,
    float* __restrict__ wnorm, float* __restrict__ S,
    float* __restrict__ count, float* __restrict__ sum_min)
{
    const int blk = blockIdx.x, tid = threadIdx.x;
    if (blk < 2048) {
        int i = blk * 256 + tid;
        float4 v = ((const float4*)A)[i];
        float vv[4] = {v.x, v.y, v.z, v.w};
        union { _Float16 h[4]; uint64_t u64; } H;
        #pragma unroll
        for (int j = 0; j < 4; j++) H.h[j] = (_Float16)vv[j];
        ((uint64_t*)Ahi)[i] = H.u64;
    } else if (blk < 6144) {
        int n = (blk - 2048) * 4 + (tid >> 6);
        int t = tid & 63;
        const float* row = W + (size_t)n * D_;
        float4 a = ((const float4*)row)[t];
        float4 b = ((const float4*)row)[t + 64];
        float av[4] = {a.x, a.y, a.z, a.w}, bv[4] = {b.x, b.y, b.z, b.w};
        union { _Float16 h[4]; uint64_t u64; } Ha, Hb;
        #pragma unroll
        for (int j = 0; j < 4; j++) { Ha.h[j] = (_Float16)av[j]; Hb.h[j] = (_Float16)bv[j]; }
        ((uint64_t*)(Whi + (size_t)n * D_))[t]       = Ha.u64;
        ((uint64_t*)(Whi + (size_t)n * D_ + 256))[t] = Hb.u64;
        float s = a.x*a.x + a.y*a.y + a.z*a.z + a.w*a.w
                + b.x*b.x + b.y*b.y + b.z*b.z + b.w*b.w;
        #pragma unroll
        for (int off = 32; off > 0; off >>= 1) s += __shfl_down(s, off, 64);
        if (t == 0) wnorm[n] = s;
    } else if (blk < 6160) {
        if (blk == 6144 && tid < 65) sum_min[tid] = 0.f;
        int j = (blk - 6144) * 256 + tid;
        float4 z = {0.f, 0.f, 0.f, 0.f};
        ((float4*)count)[j] = z;
    } else {
        size_t i = (size_t)(blk - 6160) * 256 + tid;
        float4 z = {0.f, 0.f, 0.f, 0.f};
        ((float4*)S)[i] = z;
    }
}

__global__ __launch_bounds__(512, 2) void score_mfma_kernel(
    const _Float16* __restrict__ Ah, const _Float16* __restrict__ Wh,
    const float* __restrict__ wnorm,
    const int* __restrict__ labels, const int* __restrict__ clabels,
    float* __restrict__ pminv, int* __restrict__ pmini,
    float* __restrict__ pcminv, int* __restrict__ pcmini)
{
    score_tile_body(blockIdx.x, Ah, Wh, wnorm, labels, clabels,
                    pminv, pmini, pcminv, pcmini);
}

__global__ __launch_bounds__(256) void reduce_kernel(
    const float* __restrict__ A, const float* __restrict__ W,
    const float* __restrict__ crel,
    const float* __restrict__ pminv, const int* __restrict__ pmini,
    const float* __restrict__ pcminv, const int* __restrict__ pcmini,
    int* __restrict__ bmu, float* __restrict__ sum_min, float* __restrict__ out0,
    float* __restrict__ S, float* __restrict__ count)
{
    __shared__ int sbn[4];
    const int b = blockIdx.x * 4 + (threadIdx.x >> 6);
    const int l = threadIdx.x & 63;

    size_t p = (size_t)b * NTP + l;
    unsigned long long bb = packmin(pminv[p], pmini[p]);
    unsigned long long cb = packmin(pcminv[p], pcmini[p]);

    const float* arow = A + (size_t)b * D_;
    float4 xa = ((const float4*)arow)[l];
    float4 xb = ((const float4*)arow)[l + 64];
    float xs = xa.x*xa.x + xa.y*xa.y + xa.z*xa.z + xa.w*xa.w
             + xb.x*xb.x + xb.y*xb.y + xb.z*xb.z + xb.w*xb.w;

    #pragma unroll
    for (int off = 1; off < 64; off <<= 1) {
        unsigned long long ob = __shfl_xor(bb, off, 64);
        bb = bb < ob ? bb : ob;
        unsigned long long oc = __shfl_xor(cb, off, 64);
        cb = cb < oc ? cb : oc;
        xs += __shfl_xor(xs, off, 64);
    }

    float bv; int bn; unpackmin(bb, &bv, &bn);
    float cv; int cn; unpackmin(cb, &cv, &cn);

    if (l == 0) {
        bmu[b] = bn;
        sbn[threadIdx.x >> 6] = bn;
        float md = xs + bv;
        if (md < 0.f) md = 0.f;
        atomicAdd(&sum_min[b & 63], md);
        atomicAdd(&count[bn], 1.0f);
    }

    float r = crel[cn] / 100.0f;
    float sc = (r >= THR_) ? 0.01f * r : 0.f;
    const float* wrow = W + (size_t)cn * D_;
    float4 wa = ((const float4*)wrow)[l];
    float4 wb = ((const float4*)wrow)[l + 64];
    float4 oa, ob4;
    oa.x = sc * (wa.x - xa.x); oa.y = sc * (wa.y - xa.y);
    oa.z = sc * (wa.z - xa.z); oa.w = sc * (wa.w - xa.w);
    ob4.x = sc * (wb.x - xb.x); ob4.y = sc * (wb.y - xb.y);
    ob4.z = sc * (wb.z - xb.z); ob4.w = sc * (wb.w - xb.w);
    float* orow = out0 + (size_t)b * D_;
    ((float4*)orow)[l]      = oa;
    ((float4*)orow)[l + 64] = ob4;

    __syncthreads();
    const int base_b = blockIdx.x * 4;
    #pragma unroll
    for (int rr = 0; rr < 4; rr++) {
        int bm = sbn[rr];
        const float* ar = A + (size_t)(base_b + rr) * D_;
        float* Sr = S + (size_t)bm * D_;
        atomicAdd(&Sr[threadIdx.x],       ar[threadIdx.x]);
        atomicAdd(&Sr[threadIdx.x + 256], ar[threadIdx.x + 256]);
    }
}

__global__ __launch_bounds__(256) void final_kernel(
    const float* __restrict__ som, const float* __restrict__ S,
    const float* __restrict__ count, const float* __restrict__ sum_min,
    const int* __restrict__ epoch_p, const int* __restrict__ maxep_p,
    float* __restrict__ out1)
{
    __shared__ float gsum;
    if (threadIdx.x == 0) {
        float s = 0.f;
        for (int i = 0; i < 64; i++) s += sum_min[i];
        gsum = s;
    }
    __syncthreads();

    const int o = blockIdx.x;
    const int vb = ((o & 7) << 10) | (o >> 3);
    size_t i4 = (size_t)vb * 256 + threadIdx.x;
    int n = (int)(i4 >> 7);
    int d4 = (int)(i4 & 127);
    float4 s = ((const float4*)som)[i4];
    bool gate = gsum > 1e-4f * (float)B_;
    float4 ov = s;
    if (gate) {
        int ep = epoch_p[0], me = maxep_p[0];
        float progress = (me > 0) ? (float)(me - ep) / (float)me : 0.f;
        progress = fminf(fmaxf(progress, 0.f), 1.f);
        float p2 = progress * progress;
        int ctx = (int)(p2 * p2 * 2.0f);
        float lr = 0.05f + progress * 0.15f;

        int i = n / G_, j = n % G_;
        float4 nu = {0.f, 0.f, 0.f, 0.f};
        float dn = 0.f;
        for (int di = -ctx; di <= ctx; di++) {
            int ia = i - di; if (ia < 0 || ia >= G_) continue;
            for (int dj = -ctx; dj <= ctx; dj++) {
                int jb = j - dj; if (jb < 0 || jb >= G_) continue;
                int ad = abs(di), aj = abs(dj);
                int cheb = ad > aj ? ad : aj;
                float coef = ldexpf(lr, -cheb);
                float4 t4 = ((const float4*)S)[(size_t)(jb * G_ + ia) * 128 + d4];
                nu.x += coef * t4.x; nu.y += coef * t4.y;
                nu.z += coef * t4.z; nu.w += coef * t4.w;
                dn += coef * count[jb * G_ + ia];
            }
        }
        ov.x = s.x + nu.x - s.x * dn;
        ov.y = s.y + nu.y - s.y * dn;
        ov.z = s.z + nu.z - s.z * dn;
        ov.w = s.w + nu.w - s.w * dn;
    }
    ((float4*)out1)[i4] = ov;
}

extern "C" void kernel_launch(void* const* d_in, const int* in_sizes, int n_in,
                              void* d_out, int out_size, void* d_ws, size_t ws_size,
                              hipStream_t stream) {
    const float* A   = (const float*)d_in[0];   // activations [B][D]
    const int*   lab = (const int*)d_in[1];     // labels [B]
    const float* W   = (const float*)d_in[2];   // som_vectors [G*G][D]
    const int*   cl  = (const int*)d_in[3];     // cell_labels [G*G]
    const float* cr  = (const float*)d_in[4];   // cell_reliability [G*G]
    const int*   ep  = (const int*)d_in[5];     // epoch
    const int*   me  = (const int*)d_in[6];     // max_epochs

    float* out0 = (float*)d_out;                // som_errors [B][D]
    float* out1 = out0 + (size_t)B_ * D_;       // new_som [G*G][D]

    const size_t MB = 1024 * 1024;
    uint8_t* w = (uint8_t*)d_ws;
    _Float16* Ahi  = (_Float16*)(w);                    //  4 MB
    _Float16* Whi  = (_Float16*)(w + 4 * MB);           // 16 MB
    float* pminv   = (float*)(w + 32 * MB);             //  1 MB used
    int*   pmini   = (int*)  (w + 34 * MB);             //  1 MB used
    float* pcminv  = (float*)(w + 36 * MB);             //  1 MB used
    int*   pcmini  = (int*)  (w + 38 * MB);             //  1 MB used
    float* wnorm   = (float*)(w + 40 * MB);             // 64 KB
    float* count   = (float*)(w + 40 * MB + 128 * 1024);// 64 KB
    int*   bmu     = (int*)  (w + 40 * MB + 192 * 1024);// 64 KB
    float* sum_min = (float*)(w + 40 * MB + 256 * 1024);// 65 floats: 64 buckets + total

    const int fusedS = (ws_size >= 80 * MB) ? 1 : 0;
    float* S = fusedS ? (float*)(w + 48 * MB) : (float*)w;

    static int coop = -1;
    if (coop < 0) {
        int dev = 0;
        (void)hipGetDevice(&dev);
        int v = 0;
        if (hipDeviceGetAttribute(&v, hipDeviceAttributeCooperativeLaunch, dev) != hipSuccess)
            v = 0;
        coop = v;
    }

    if (coop) {
        int fusedS_arg = fusedS;
        void* kargs[] = {
            (void*)&A, (void*)&lab, (void*)&W, (void*)&cl, (void*)&cr,
            (void*)&ep, (void*)&me, (void*)&Ahi, (void*)&Whi, (void*)&wnorm,
            (void*)&pminv, (void*)&pmini, (void*)&pcminv, (void*)&pcmini,
            (void*)&bmu, (void*)&sum_min, (void*)&out0, (void*)&out1,
            (void*)&S, (void*)&count, (void*)&fusedS_arg
        };
        hipLaunchCooperativeKernel((const void*)mega_kernel, dim3(256), dim3(512),
                                   kargs, 0, stream);
    } else {
        prep_kernel<<<fusedS ? 14352 : 6160, 256, 0, stream>>>(
            A, W, Ahi, Whi, wnorm, S, count, sum_min);

        score_mfma_kernel<<<dim3((B_ / 256) * (N_ / 256)), 512, 0, stream>>>(
            Ahi, Whi, wnorm, lab, cl, pminv, pmini, pcminv, pcmini);

        if (!fusedS)
            hipMemsetAsync(S, 0, (size_t)N_ * D_ * sizeof(float), stream);

        reduce_kernel<<<B_ / 4, 256, 0, stream>>>(A, W, cr, pminv, pmini, pcminv, pcmini,
                                                  bmu, sum_min, out0, S, count);

        final_kernel<<<(N_ * D_ / 4) / 256, 256, 0, stream>>>(
            W, S, count, sum_min, ep, me, out1);
    }
}

// Round 14
// 256.312 us; speedup vs baseline: 2.0594x; 2.0594x over previous
//
#include <hip/hip_runtime.h>
#include <math.h>

#define B_ 4096
#define D_ 512
#define G_ 128
#define N_ (G_*G_)        // 16384
#define NTP 64            // number of 256-wide n tiles (partials per row)
#define THR_ 0.95f
#define IMAX_ 0x7FFFFFFF

typedef float f32x4 __attribute__((ext_vector_type(4)));
typedef _Float16 half8 __attribute__((ext_vector_type(8)));

// ---------------- fused prep: A split + W split/wnorm + zero count/sum_min ----------------
// r14: S-zeroing moved into score epilogue (fused path) — prep grid 14352 -> 6160.
__global__ __launch_bounds__(256) void prep_kernel(
    const float* __restrict__ A, const float* __restrict__ W,
    _Float16* __restrict__ Ahi, _Float16* __restrict__ Whi,
    float* __restrict__ wnorm,
    float* __restrict__ count, float* __restrict__ sum_min)
{
    const int blk = blockIdx.x, tid = threadIdx.x;
    if (blk < 2048) {
        int i = blk * 256 + tid;
        float4 v = ((const float4*)A)[i];
        float vv[4] = {v.x, v.y, v.z, v.w};
        union { _Float16 h[4]; uint64_t u64; } H;
        #pragma unroll
        for (int j = 0; j < 4; j++) H.h[j] = (_Float16)vv[j];
        ((uint64_t*)Ahi)[i] = H.u64;
    } else if (blk < 6144) {
        int n = (blk - 2048) * 4 + (tid >> 6);
        int t = tid & 63;
        const float* row = W + (size_t)n * D_;
        float4 a = ((const float4*)row)[t];
        float4 b = ((const float4*)row)[t + 64];
        float av[4] = {a.x, a.y, a.z, a.w}, bv[4] = {b.x, b.y, b.z, b.w};
        union { _Float16 h[4]; uint64_t u64; } Ha, Hb;
        #pragma unroll
        for (int j = 0; j < 4; j++) { Ha.h[j] = (_Float16)av[j]; Hb.h[j] = (_Float16)bv[j]; }
        ((uint64_t*)(Whi + (size_t)n * D_))[t]       = Ha.u64;
        ((uint64_t*)(Whi + (size_t)n * D_ + 256))[t] = Hb.u64;
        float s = a.x*a.x + a.y*a.y + a.z*a.z + a.w*a.w
                + b.x*b.x + b.y*b.y + b.z*b.z + b.w*b.w;
        #pragma unroll
        for (int off = 32; off > 0; off >>= 1) s += __shfl_down(s, off, 64);
        if (t == 0) wnorm[n] = s;
    } else {
        if (blk == 6144 && tid < 65) sum_min[tid] = 0.f;
        int j = (blk - 6144) * 256 + tid;              // 16 blocks: 4096 float4 = count
        float4 z = {0.f, 0.f, 0.f, 0.f};
        ((float4*)count)[j] = z;
    }
}

// ---------------- packed (value,index) helpers for argmin ----------------
__device__ __forceinline__ unsigned long long packmin(float v, int n) {
    unsigned u = __float_as_uint(v);
    u ^= (u & 0x80000000u) ? 0xFFFFFFFFu : 0x80000000u;
    return ((unsigned long long)u << 32) | (unsigned)n;
}
__device__ __forceinline__ void unpackmin(unsigned long long pkt, float* v, int* n) {
    unsigned u = (unsigned)(pkt >> 32);
    u = (u & 0x80000000u) ? (u ^ 0x80000000u) : ~u;
    *v = __uint_as_float(u);
    *n = (int)(unsigned)pkt;
}

// ---------------- MFMA score GEMM: 256x256 tile, 8 waves, r7/r11-proven 4-phase ----------------
// Verified control: 103-105us, MfmaUtil ~27%, absmax 0.546875. r12 (repipelining) and r13
// (cooperative fusion) both failed — this structure is the plateau; do not touch.
// r14 addition: fused-S path zeroes S slices in the epilogue (removes 8192 prep blocks).

#define PH_WAIT_(N) asm volatile("s_waitcnt vmcnt(" #N ")" ::: "memory")
#define PH_WAIT(N) PH_WAIT_(N)
#define WAITLGKM0 asm volatile("s_waitcnt lgkmcnt(0)" ::: "memory")
#define SBAR __builtin_amdgcn_s_barrier()
#define SCHED0 __builtin_amdgcn_sched_barrier(0)
#define PRIO1 __builtin_amdgcn_s_setprio(1)
#define PRIO0 __builtin_amdgcn_s_setprio(0)

#define STAGE_HALF(GBASE, LOFF, TAU, H) do { \
    __builtin_amdgcn_global_load_lds( \
        (const __attribute__((address_space(1))) void*)((GBASE) + (size_t)(H) * (128 * D_) + (TAU) * 64 + srcoff0), \
        (__attribute__((address_space(3))) void*)(smem + (LOFF) + (((TAU) & 1) << 15) + ((H) << 14) + ldsoff0), 16, 0, 0); \
    __builtin_amdgcn_global_load_lds( \
        (const __attribute__((address_space(1))) void*)((GBASE) + (size_t)(H) * (128 * D_) + (TAU) * 64 + srcoff1), \
        (__attribute__((address_space(3))) void*)(smem + (LOFF) + (((TAU) & 1) << 15) + ((H) << 14) + ldsoff1), 16, 0, 0); \
} while (0)

#define TILE(TAU, S1, S3, S4, DO_W, VM4) do { \
    half8 af[4][2], bl[2][2], bh[2][2]; \
    _Pragma("unroll") for (int mi = 0; mi < 4; mi++) { \
        af[mi][0] = *(const half8*)(smem + (((TAU) & 1) << 15) + sA + mi * 2048 + swz0); \
        af[mi][1] = *(const half8*)(smem + (((TAU) & 1) << 15) + sA + mi * 2048 + swz1); } \
    _Pragma("unroll") for (int ni = 0; ni < 2; ni++) { \
        bl[ni][0] = *(const half8*)(smem + 65536 + (((TAU) & 1) << 15) + sB + ni * 2048 + swz0); \
        bl[ni][1] = *(const half8*)(smem + 65536 + (((TAU) & 1) << 15) + sB + ni * 2048 + swz1); } \
    if (S1) STAGE_HALF(Abase, 0, (TAU) + 1, 1); \
    SBAR; WAITLGKM0; SCHED0; PRIO1; \
    _Pragma("unroll") for (int mi = 0; mi < 4; mi++) \
      _Pragma("unroll") for (int ni = 0; ni < 2; ni++) { \
        acc[mi][ni] = __builtin_amdgcn_mfma_f32_16x16x32_f16(af[mi][0], bl[ni][0], acc[mi][ni], 0, 0, 0); \
        acc[mi][ni] = __builtin_amdgcn_mfma_f32_16x16x32_f16(af[mi][1], bl[ni][1], acc[mi][ni], 0, 0, 0); } \
    PRIO0; SCHED0; SBAR; \
    _Pragma("unroll") for (int ni = 0; ni < 2; ni++) { \
        bh[ni][0] = *(const half8*)(smem + 65536 + (((TAU) & 1) << 15) + sB + (ni + 2) * 2048 + swz0); \
        bh[ni][1] = *(const half8*)(smem + 65536 + (((TAU) & 1) << 15) + sB + (ni + 2) * 2048 + swz1); } \
    SBAR; WAITLGKM0; SCHED0; PRIO1; \
    _Pragma("unroll") for (int mi = 0; mi < 4; mi++) \
      _Pragma("unroll") for (int ni = 0; ni < 2; ni++) { \
        acc[mi][ni + 2] = __builtin_amdgcn_mfma_f32_16x16x32_f16(af[mi][0], bh[ni][0], acc[mi][ni + 2], 0, 0, 0); \
        acc[mi][ni + 2] = __builtin_amdgcn_mfma_f32_16x16x32_f16(af[mi][1], bh[ni][1], acc[mi][ni + 2], 0, 0, 0); } \
    PRIO0; SCHED0; SBAR; \
    _Pragma("unroll") for (int mi = 0; mi < 4; mi++) { \
        af[mi][0] = *(const half8*)(smem + (((TAU) & 1) << 15) + sA + (mi + 4) * 2048 + swz0); \
        af[mi][1] = *(const half8*)(smem + (((TAU) & 1) << 15) + sA + (mi + 4) * 2048 + swz1); } \
    if (S3) STAGE_HALF(Wbase, 65536, (TAU) + 2, 0); \
    SBAR; WAITLGKM0; SCHED0; PRIO1; \
    _Pragma("unroll") for (int mi = 0; mi < 4; mi++) \
      _Pragma("unroll") for (int ni = 0; ni < 2; ni++) { \
        acc[mi + 4][ni + 2] = __builtin_amdgcn_mfma_f32_16x16x32_f16(af[mi][0], bh[ni][0], acc[mi + 4][ni + 2], 0, 0, 0); \
        acc[mi + 4][ni + 2] = __builtin_amdgcn_mfma_f32_16x16x32_f16(af[mi][1], bh[ni][1], acc[mi + 4][ni + 2], 0, 0, 0); } \
    PRIO0; SCHED0; SBAR; \
    if (S4) { STAGE_HALF(Abase, 0, (TAU) + 2, 0); STAGE_HALF(Wbase, 65536, (TAU) + 2, 1); } \
    if (DO_W) PH_WAIT(VM4); \
    SBAR; PRIO1; \
    _Pragma("unroll") for (int mi = 0; mi < 4; mi++) \
      _Pragma("unroll") for (int ni = 0; ni < 2; ni++) { \
        acc[mi + 4][ni] = __builtin_amdgcn_mfma_f32_16x16x32_f16(af[mi][0], bl[ni][0], acc[mi + 4][ni], 0, 0, 0); \
        acc[mi + 4][ni] = __builtin_amdgcn_mfma_f32_16x16x32_f16(af[mi][1], bl[ni][1], acc[mi + 4][ni], 0, 0, 0); } \
    PRIO0; SCHED0; SBAR; \
} while (0)

__global__ __launch_bounds__(512, 2) void score_mfma_kernel(
    const _Float16* __restrict__ Ah, const _Float16* __restrict__ Wh,
    const float* __restrict__ wnorm,
    const int* __restrict__ labels, const int* __restrict__ clabels,
    float* __restrict__ pminv, int* __restrict__ pmini,
    float* __restrict__ pcminv, int* __restrict__ pcmini,
    float* __restrict__ S, int zeroS)
{
    __shared__ __align__(16) char smem[131072];  // A: 2x32KB @0, B: 2x32KB @64KB

    const int tid  = threadIdx.x;
    const int lane = tid & 63;
    const int wave = tid >> 6;
    const int wm = wave >> 2, wn = wave & 3;     // 2M x 4N wave grid; 128x64 per wave
    const int c = lane & 15, quad = lane >> 4;

    const int o = blockIdx.x;
    const int xcd = o & 7, idx = o >> 3;
    const int ntile = (xcd << 3) | (idx & 7);
    const int mtile = idx >> 3;
    const int m0 = mtile * 256, n0 = ntile * 256;

    const _Float16* Abase = Ah + (size_t)m0 * D_;
    const _Float16* Wbase = Wh + (size_t)n0 * D_;

    const int i0 = tid, i1 = 512 + tid;
    const int rl0 = i0 >> 3, sl0 = i0 & 7, rl1 = i1 >> 3, sl1 = i1 & 7;
    const size_t srcoff0 = (size_t)rl0 * D_ + ((sl0 ^ (rl0 & 7)) << 3);
    const size_t srcoff1 = (size_t)rl1 * D_ + ((sl1 ^ (rl1 & 7)) << 3);
    const int ldsoff0 = i0 << 4, ldsoff1 = i1 << 4;

    const int sA = (wm * 128 + c) * 128;
    const int sB = (wn * 64 + c) * 128;
    const int swz0 = ((0 * 4 + quad) ^ (c & 7)) << 4;   // kk=0
    const int swz1 = ((1 * 4 + quad) ^ (c & 7)) << 4;   // kk=1

    f32x4 acc[8][4];
    #pragma unroll
    for (int i = 0; i < 8; i++)
        #pragma unroll
        for (int j = 0; j < 4; j++)
            acc[i][j] = (f32x4){0.f, 0.f, 0.f, 0.f};

    STAGE_HALF(Abase, 0, 0, 0);
    STAGE_HALF(Wbase, 65536, 0, 0);
    STAGE_HALF(Wbase, 65536, 0, 1);
    STAGE_HALF(Abase, 0, 0, 1);
    STAGE_HALF(Abase, 0, 1, 0);
    STAGE_HALF(Wbase, 65536, 1, 0);
    STAGE_HALF(Wbase, 65536, 1, 1);
    PH_WAIT(6); SBAR;

    TILE(0, 1, 1, 1, 1, 6);
    TILE(1, 1, 1, 1, 1, 6);
    TILE(2, 1, 1, 1, 1, 6);
    TILE(3, 1, 1, 1, 1, 6);
    TILE(4, 1, 1, 1, 1, 6);
    TILE(5, 1, 1, 1, 1, 6);
    TILE(6, 1, 0, 0, 1, 0);
    TILE(7, 0, 0, 0, 0, 0);

    __syncthreads();   // GEMM done; reuse smem as [256][64] u64 candidate table

    const unsigned long long ID = (0xFF800000ull << 32) | 0x7FFFFFFFull;  // (+inf, IMAX)
    float wnl[4]; int cll[4];
    #pragma unroll
    for (int ni = 0; ni < 4; ni++) {
        int n = n0 + wn * 64 + ni * 16 + c;
        wnl[ni] = wnorm[n];
        cll[ni] = clabels[n];
    }

    unsigned long long (*tbl)[64] = (unsigned long long (*)[64])smem;  // 128KB exactly
    unsigned long long cbst[8][4];

    #pragma unroll
    for (int mi = 0; mi < 8; mi++) {
        #pragma unroll
        for (int r = 0; r < 4; r++) {
            int rowl = wm * 128 + mi * 16 + quad * 4 + r;   // 0..255 in block
            int lb = labels[m0 + rowl];
            unsigned long long bb = ID, cb = ID;
            #pragma unroll
            for (int ni = 0; ni < 4; ni++) {
                float s = fmaf(-2.f, acc[mi][ni][r], wnl[ni]);
                unsigned long long pk = packmin(s, n0 + wn * 64 + ni * 16 + c);
                bb = bb < pk ? bb : pk;
                if (cll[ni] == lb) cb = cb < pk ? cb : pk;
            }
            tbl[rowl][(wn * 16 + c) ^ (rowl & 15)] = bb;   // XOR slot: caps conflicts 4-way
            cbst[mi][r] = cb;
        }
    }
    __syncthreads();
    if (tid < 256) {
        int row = tid;
        unsigned long long m = ID;
        #pragma unroll
        for (int j = 0; j < 64; j++) {
            unsigned long long v = tbl[row][j ^ (row & 15)];
            m = m < v ? m : v;
        }
        float v; int n; unpackmin(m, &v, &n);
        size_t pp = (size_t)(m0 + row) * NTP + ntile;
        pminv[pp] = v; pmini[pp] = n;
    }
    __syncthreads();
    #pragma unroll
    for (int mi = 0; mi < 8; mi++)
        #pragma unroll
        for (int r = 0; r < 4; r++) {
            int rowl = wm * 128 + mi * 16 + quad * 4 + r;
            tbl[rowl][(wn * 16 + c) ^ (rowl & 15)] = cbst[mi][r];
        }
    __syncthreads();
    if (tid < 256) {
        int row = tid;
        unsigned long long m = ID;
        #pragma unroll
        for (int j = 0; j < 64; j++) {
            unsigned long long v = tbl[row][j ^ (row & 15)];
            m = m < v ? m : v;
        }
        float v; int n; unpackmin(m, &v, &n);
        size_t pp = (size_t)(m0 + row) * NTP + ntile;
        pcminv[pp] = v; pcmini[pp] = n;
    }

    // r14: zero this block's 1/1024 slice of S (fused-S layout only; non-aliased).
    if (zeroS) {
        const float4 z = {0.f, 0.f, 0.f, 0.f};
        float4* Sz = (float4*)(S + (size_t)o * 8192);
        #pragma unroll
        for (int k = 0; k < 4; k++)
            Sz[k * 512 + tid] = z;
    }
}

// ---------------- reduce + scatter: one wave per row, then block-cooperative scatter ----------------
__global__ __launch_bounds__(256) void reduce_kernel(
    const float* __restrict__ A, const float* __restrict__ W,
    const float* __restrict__ crel,
    const float* __restrict__ pminv, const int* __restrict__ pmini,
    const float* __restrict__ pcminv, const int* __restrict__ pcmini,
    float* __restrict__ sum_min, float* __restrict__ out0,
    float* __restrict__ S, float* __restrict__ count)
{
    __shared__ int sbn[4];
    const int b = blockIdx.x * 4 + (threadIdx.x >> 6);
    const int l = threadIdx.x & 63;

    size_t p = (size_t)b * NTP + l;
    unsigned long long bb = packmin(pminv[p], pmini[p]);
    unsigned long long cb = packmin(pcminv[p], pcmini[p]);

    const float* arow = A + (size_t)b * D_;
    float4 xa = ((const float4*)arow)[l];
    float4 xb = ((const float4*)arow)[l + 64];
    float xs = xa.x*xa.x + xa.y*xa.y + xa.z*xa.z + xa.w*xa.w
             + xb.x*xb.x + xb.y*xb.y + xb.z*xb.z + xb.w*xb.w;

    #pragma unroll
    for (int off = 1; off < 64; off <<= 1) {
        unsigned long long ob = __shfl_xor(bb, off, 64);
        bb = bb < ob ? bb : ob;
        unsigned long long oc = __shfl_xor(cb, off, 64);
        cb = cb < oc ? cb : oc;
        xs += __shfl_xor(xs, off, 64);
    }

    float bv; int bn; unpackmin(bb, &bv, &bn);
    float cv; int cn; unpackmin(cb, &cv, &cn);

    if (l == 0) {
        sbn[threadIdx.x >> 6] = bn;
        float md = xs + bv;
        if (md < 0.f) md = 0.f;
        atomicAdd(&sum_min[b & 63], md);
        atomicAdd(&count[bn], 1.0f);
    }

    float r = crel[cn] / 100.0f;
    float sc = (r >= THR_) ? 0.01f * r : 0.f;
    const float* wrow = W + (size_t)cn * D_;
    float4 wa = ((const float4*)wrow)[l];
    float4 wb = ((const float4*)wrow)[l + 64];
    float4 oa, ob4;
    oa.x = sc * (wa.x - xa.x); oa.y = sc * (wa.y - xa.y);
    oa.z = sc * (wa.z - xa.z); oa.w = sc * (wa.w - xa.w);
    ob4.x = sc * (wb.x - xb.x); ob4.y = sc * (wb.y - xb.y);
    ob4.z = sc * (wb.z - xb.z); ob4.w = sc * (wb.w - xb.w);
    float* orow = out0 + (size_t)b * D_;
    ((float4*)orow)[l]      = oa;
    ((float4*)orow)[l + 64] = ob4;

    __syncthreads();
    const int base_b = blockIdx.x * 4;
    #pragma unroll
    for (int rr = 0; rr < 4; rr++) {
        int bm = sbn[rr];
        const float* ar = A + (size_t)(base_b + rr) * D_;
        float* Sr = S + (size_t)bm * D_;
        atomicAdd(&Sr[threadIdx.x],       ar[threadIdx.x]);
        atomicAdd(&Sr[threadIdx.x + 256], ar[threadIdx.x + 256]);
    }
}

// ---------------- final: out1 = som + stencil(S) - som*denom (gated); denom inlined ----------------
__global__ __launch_bounds__(256) void final_kernel(
    const float* __restrict__ som, const float* __restrict__ S,
    const float* __restrict__ count, const float* __restrict__ sum_min,
    const int* __restrict__ epoch_p, const int* __restrict__ maxep_p,
    float* __restrict__ out1)
{
    __shared__ float gsum;
    if (threadIdx.x == 0) {
        float s = 0.f;
        for (int i = 0; i < 64; i++) s += sum_min[i];
        gsum = s;
    }
    __syncthreads();

    const int o = blockIdx.x;                      // 8192 blocks
    const int vb = ((o & 7) << 10) | (o >> 3);     // xcd*1024 + idx  (bijective)
    size_t i4 = (size_t)vb * 256 + threadIdx.x;
    int n = (int)(i4 >> 7);          // 128 float4 per cell row
    int d4 = (int)(i4 & 127);
    float4 s = ((const float4*)som)[i4];
    bool gate = gsum > 1e-4f * (float)B_;   // mean(min_dists) > 1e-4
    float4 ov = s;
    if (gate) {
        int ep = epoch_p[0], me = maxep_p[0];
        float progress = (me > 0) ? (float)(me - ep) / (float)me : 0.f;
        progress = fminf(fmaxf(progress, 0.f), 1.f);
        float p2 = progress * progress;
        int ctx = (int)(p2 * p2 * 2.0f);
        float lr = 0.05f + progress * 0.15f;

        int i = n / G_, j = n % G_;
        float4 nu = {0.f, 0.f, 0.f, 0.f};
        float dn = 0.f;
        for (int di = -ctx; di <= ctx; di++) {
            int ia = i - di; if (ia < 0 || ia >= G_) continue;
            for (int dj = -ctx; dj <= ctx; dj++) {
                int jb = j - dj; if (jb < 0 || jb >= G_) continue;
                int ad = abs(di), aj = abs(dj);
                int cheb = ad > aj ? ad : aj;
                float coef = ldexpf(lr, -cheb);
                float4 t4 = ((const float4*)S)[(size_t)(jb * G_ + ia) * 128 + d4];
                nu.x += coef * t4.x; nu.y += coef * t4.y;
                nu.z += coef * t4.z; nu.w += coef * t4.w;
                dn += coef * count[jb * G_ + ia];
            }
        }
        ov.x = s.x + nu.x - s.x * dn;
        ov.y = s.y + nu.y - s.y * dn;
        ov.z = s.z + nu.z - s.z * dn;
        ov.w = s.w + nu.w - s.w * dn;
    }
    ((float4*)out1)[i4] = ov;
}

extern "C" void kernel_launch(void* const* d_in, const int* in_sizes, int n_in,
                              void* d_out, int out_size, void* d_ws, size_t ws_size,
                              hipStream_t stream) {
    const float* A   = (const float*)d_in[0];   // activations [B][D]
    const int*   lab = (const int*)d_in[1];     // labels [B]
    const float* W   = (const float*)d_in[2];   // som_vectors [G*G][D]
    const int*   cl  = (const int*)d_in[3];     // cell_labels [G*G]
    const float* cr  = (const float*)d_in[4];   // cell_reliability [G*G]
    const int*   ep  = (const int*)d_in[5];     // epoch
    const int*   me  = (const int*)d_in[6];     // max_epochs

    float* out0 = (float*)d_out;                // som_errors [B][D]
    float* out1 = out0 + (size_t)B_ * D_;       // new_som [G*G][D]

    const size_t MB = 1024 * 1024;
    uint8_t* w = (uint8_t*)d_ws;
    _Float16* Ahi  = (_Float16*)(w);                    //  4 MB
    _Float16* Whi  = (_Float16*)(w + 4 * MB);           // 16 MB
    float* pminv   = (float*)(w + 32 * MB);             //  1 MB used
    int*   pmini   = (int*)  (w + 34 * MB);             //  1 MB used
    float* pcminv  = (float*)(w + 36 * MB);             //  1 MB used
    int*   pcmini  = (int*)  (w + 38 * MB);             //  1 MB used
    float* wnorm   = (float*)(w + 40 * MB);             // 64 KB
    float* count   = (float*)(w + 40 * MB + 128 * 1024);// 64 KB
    float* sum_min = (float*)(w + 40 * MB + 256 * 1024);// 65 floats: 64 buckets + total

    // S: non-aliased at [48,80) MB if workspace allows (zeroed in score epilogue);
    // else aliases the dead f16 region and is zeroed by a stream-ordered memset.
    const int fusedS = (ws_size >= 80 * MB) ? 1 : 0;
    float* S = fusedS ? (float*)(w + 48 * MB) : (float*)w;

    prep_kernel<<<6160, 256, 0, stream>>>(A, W, Ahi, Whi, wnorm, count, sum_min);

    score_mfma_kernel<<<dim3((B_ / 256) * (N_ / 256)), 512, 0, stream>>>(
        Ahi, Whi, wnorm, lab, cl, pminv, pmini, pcminv, pcmini, S, fusedS);

    if (!fusedS)
        hipMemsetAsync(S, 0, (size_t)N_ * D_ * sizeof(float), stream);

    reduce_kernel<<<B_ / 4, 256, 0, stream>>>(A, W, cr, pminv, pmini, pcminv, pcmini,
                                              sum_min, out0, S, count);

    final_kernel<<<(N_ * D_ / 4) / 256, 256, 0, stream>>>(
        W, S, count, sum_min, ep, me, out1);
}